// Round 1
// 203.606 us; speedup vs baseline: 1.0056x; 1.0056x over previous
//
#include <hip/hip_runtime.h>
#include <math.h>

namespace {

constexpr int kB   = 64;
constexpr int kCin = 8;
constexpr int kR   = 800;
constexpr int kNC  = 128;
constexpr int kO   = 16;
constexpr int CT   = 256;   // conversion kernel TPB
constexpr int MT   = 512;   // main kernel TPB
constexpr int NITER = 3;
constexpr size_t WS_NEEDED =
    (size_t)kNC * kO * kR * kCin * sizeof(unsigned short);  // 26,214,400 B

typedef _Float16 half2v __attribute__((ext_vector_type(2)));

__device__ __forceinline__ half2v u2h(unsigned int u) {
  union { unsigned int u; half2v h; } x;
  x.u = u;
  return x.h;
}

__device__ __forceinline__ unsigned short f2h(float f) {
  union { _Float16 h; unsigned short s; } x;
  x.h = (_Float16)f;
  return x.s;
}

// DPP quad-perm adds: xor1 = perm{1,0,3,2} = 0xB1, xor2 = perm{2,3,0,1} = 0x4E.
__device__ __forceinline__ float dpp_xor1_add(float v) {
  const int o = __builtin_amdgcn_mov_dpp(__float_as_int(v), 0xB1, 0xF, 0xF, true);
  return v + __int_as_float(o);
}
__device__ __forceinline__ float dpp_xor2_add(float v) {
  const int o = __builtin_amdgcn_mov_dpp(__float_as_int(v), 0x4E, 0xF, 0xF, true);
  return v + __int_as_float(o);
}

// ---- W conversion: fp32 [c][r][i][o] -> fp16 [c][o][r][i] (uint4 = 8 i's) --
// R8: streaming 32-row tiles. LDS 16.9 KB -> 8 blocks/CU (100% occupancy),
// grid 3200 blocks (was 1280 @ 42 KB LDS / 3 blocks/CU -> latency-starved).
// Same 132-stride pad layout as the proven 80-row version (2-way max conflict).
__global__ __launch_bounds__(CT) void conv_w(const float* __restrict__ W,
                                             unsigned short* __restrict__ Wb) {
  __shared__ float tile[32 * 132];   // 32 r-rows x 128 cols (+4 pad) = 16.9 KB
  const int blk = blockIdx.x;        // c*25 + rt
  const int c  = blk / 25;
  const int rt = blk - c * 25;
  const int r0 = rt * 32;
  const int t  = threadIdx.x;

  const float4* src =
      reinterpret_cast<const float4*>(W + ((size_t)c * kR + r0) * kCin * kO);
  #pragma unroll
  for (int k2 = 0; k2 < 4; ++k2) {
    const int i4  = t + k2 * CT;           // 0..1023 float4 = 32*128 floats
    const float4 v = src[i4];
    const int fi = i4 * 4, row = fi >> 7, pos = fi & 127;
    *reinterpret_cast<float4*>(&tile[row * 132 + pos]) = v;
  }
  __syncthreads();

  const int o = t >> 4;
  #pragma unroll
  for (int k2 = 0; k2 < 2; ++k2) {
    const int rl = (t & 15) + 16 * k2;
    unsigned int pk[4];
    #pragma unroll
    for (int q = 0; q < 4; ++q) {
      const unsigned int lo = f2h(tile[rl * 132 + (2 * q + 0) * 16 + o]);
      const unsigned int hi = f2h(tile[rl * 132 + (2 * q + 1) * 16 + o]);
      pk[q] = lo | (hi << 16);
    }
    reinterpret_cast<uint4*>(Wb)[(size_t)(c * kO + o) * kR + (r0 + rl)] =
        make_uint4(pk[0], pk[1], pk[2], pk[3]);
  }
}

// ---- main: R7 structure, but priors kept UNPACKED fp32 (removes 3x32 cvt
// unpacks + phase-1 pack, ~120 VALU/thread). VGPR 64 -> ~100; achieved
// occupancy (42% = 13.4 waves/CU) is below even the 20-wave ceiling this
// implies, so no occupancy loss expected. ----
__global__ __launch_bounds__(MT, 4) void caps_route(
    const float* __restrict__ x, const unsigned short* __restrict__ Wb,
    float* __restrict__ out) {
  constexpr int RST = 20;               // 17 cols + 3 pad (16B-aligned rows)
  __shared__ float red[128 * RST];      // 10 KB
  __shared__ float red2[8 * RST];
  __shared__ float shs[RST];

  const int t = threadIdx.x;
  // XCD swizzle: 16 c's per XCD -> fp16 W working set 3.3 MB < 4 MB L2.
  const int j   = blockIdx.x;
  const int xcd = j & 7;
  const int kk  = j >> 3;               // 0..1023
  const int c   = ((kk >> 6) << 3) + xcd;
  const int b   = kk & 63;

  const float* xb  = x + (size_t)b * kCin * kR;
  const bool  has2 = (t < kR - MT);     // t < 288 owns second row r2
  const int   r1   = t, r2 = MT + t;

  float P1[kO], P2[kO];
  #pragma unroll
  for (int o = 0; o < kO; ++o) P2[o] = 0.f;

  const uint4* Wc = reinterpret_cast<const uint4*>(Wb) + (size_t)c * kO * kR;

  // -------- Phase 1: fdot2 rows; explicit 8-deep load chunks ----------------
  {
    half2v xp[4];
    #pragma unroll
    for (int q = 0; q < 4; ++q)
      xp[q] = half2v{(_Float16)xb[(2*q) * kR + r1], (_Float16)xb[(2*q+1) * kR + r1]};
    #pragma unroll
    for (int ob = 0; ob < 2; ++ob) {
      uint4 w[8];
      #pragma unroll
      for (int u = 0; u < 8; ++u) w[u] = Wc[(size_t)(ob * 8 + u) * kR + r1];
      #pragma unroll
      for (int u = 0; u < 8; ++u) {
        float a = __builtin_amdgcn_fdot2(u2h(w[u].x), xp[0], 0.f, false);
        a = __builtin_amdgcn_fdot2(u2h(w[u].y), xp[1], a, false);
        a = __builtin_amdgcn_fdot2(u2h(w[u].z), xp[2], a, false);
        a = __builtin_amdgcn_fdot2(u2h(w[u].w), xp[3], a, false);
        P1[ob * 8 + u] = a;
      }
    }
  }
  if (has2) {
    half2v xp[4];
    #pragma unroll
    for (int q = 0; q < 4; ++q)
      xp[q] = half2v{(_Float16)xb[(2*q) * kR + r2], (_Float16)xb[(2*q+1) * kR + r2]};
    #pragma unroll
    for (int ob = 0; ob < 2; ++ob) {
      uint4 w[8];
      #pragma unroll
      for (int u = 0; u < 8; ++u) w[u] = Wc[(size_t)(ob * 8 + u) * kR + r2];
      #pragma unroll
      for (int u = 0; u < 8; ++u) {
        float a = __builtin_amdgcn_fdot2(u2h(w[u].x), xp[0], 0.f, false);
        a = __builtin_amdgcn_fdot2(u2h(w[u].y), xp[1], a, false);
        a = __builtin_amdgcn_fdot2(u2h(w[u].z), xp[2], a, false);
        a = __builtin_amdgcn_fdot2(u2h(w[u].w), xp[3], a, false);
        P2[ob * 8 + u] = a;
      }
    }
  }

  // -------- Phase 2: 3 routing iterations (fp32 math, direct on P) ----------
  float l1 = 0.f, l2 = 0.f;
  #pragma unroll
  for (int it = 0; it < NITER; ++it) {
    const float e1 = (it == 0) ? 1.f : __expf(l1);
    const float e2 = has2 ? ((it == 0) ? 1.f : __expf(l2)) : 0.f;

    float sp[kO + 1];
    sp[kO] = e1 + e2;
    #pragma unroll
    for (int o = 0; o < kO; ++o) sp[o] = e1 * P1[o] + e2 * P2[o];

    #pragma unroll
    for (int v = 0; v <= kO; ++v) {
      sp[v] = dpp_xor1_add(sp[v]);
      sp[v] = dpp_xor2_add(sp[v]);
    }
    if ((t & 3) == 0) {
      float* row = &red[(t >> 2) * RST];
      #pragma unroll
      for (int q = 0; q < 4; ++q)
        *reinterpret_cast<float4*>(row + 4 * q) =
            make_float4(sp[4*q], sp[4*q+1], sp[4*q+2], sp[4*q+3]);
      row[16] = sp[16];
    }
    __syncthreads();
    if (t < 136) {   // 8 q-groups x 17 cols; stride-8 rows mix q into bank
      const int q = t / 17, col = t - q * 17;
      float a = 0.f;
      #pragma unroll
      for (int rr = 0; rr < 16; ++rr) a += red[(rr * 8 + q) * RST + col];
      red2[q * RST + col] = a;
    }
    __syncthreads();
    if (t < 17) {
      float a = 0.f;
      #pragma unroll
      for (int q = 0; q < 8; ++q) a += red2[q * RST + t];
      shs[t] = a;
    }
    __syncthreads();

    const float Zi = 1.f / shs[kO];
    float ss = 0.f;
    #pragma unroll
    for (int o = 0; o < kO; ++o) ss += shs[o] * shs[o];
    const float sn = ss * Zi * Zi;
    const float g  = Zi * sqrtf(sn) / (1.f + sn);

    if (it < NITER - 1) {
      float d1 = 0.f, d2 = 0.f;
      #pragma unroll
      for (int o = 0; o < kO; ++o) { d1 += P1[o] * shs[o]; d2 += P2[o] * shs[o]; }
      l1 += d1 * g;
      if (has2) l2 += d2 * g;
    } else {
      if (t < kO) out[(size_t)b * kO * kNC + t * kNC + c] = shs[t] * g;
    }
  }
}

// ---- fallback (no workspace): fp32 W direct ------------------------------
__global__ __launch_bounds__(MT, 4) void caps_route_f32(
    const float* __restrict__ x, const float* __restrict__ W,
    float* __restrict__ out) {
  constexpr int RST = 20;
  __shared__ float red[128 * RST];
  __shared__ float red2[8 * RST];
  __shared__ float shs[RST];

  const int t   = threadIdx.x;
  const int j   = blockIdx.x;
  const int xcd = j & 7;
  const int kk  = j >> 3;
  const int c   = ((kk >> 6) << 3) + xcd;
  const int b   = kk & 63;

  const float* xb  = x + (size_t)b * kCin * kR;
  const bool  has2 = (t < kR - MT);
  const int   r1   = t, r2 = MT + t;

  float P1[kO], P2[kO];
  #pragma unroll
  for (int o = 0; o < kO; ++o) P2[o] = 0.f;
  {
    float xa[kCin];
    #pragma unroll
    for (int i = 0; i < kCin; ++i) xa[i] = xb[i * kR + r1];
    const float* Wc = W + ((size_t)c * kR + r1) * kCin * kO;
    #pragma unroll
    for (int o = 0; o < kO; ++o) {
      float acc = 0.f;
      #pragma unroll
      for (int i = 0; i < kCin; ++i) acc += xa[i] * Wc[i * kO + o];
      P1[o] = acc;
    }
  }
  if (has2) {
    float xa[kCin];
    #pragma unroll
    for (int i = 0; i < kCin; ++i) xa[i] = xb[i * kR + r2];
    const float* Wc = W + ((size_t)c * kR + r2) * kCin * kO;
    #pragma unroll
    for (int o = 0; o < kO; ++o) {
      float acc = 0.f;
      #pragma unroll
      for (int i = 0; i < kCin; ++i) acc += xa[i] * Wc[i * kO + o];
      P2[o] = acc;
    }
  }

  float l1 = 0.f, l2 = 0.f;
  #pragma unroll
  for (int it = 0; it < NITER; ++it) {
    const float e1 = (it == 0) ? 1.f : __expf(l1);
    const float e2 = has2 ? ((it == 0) ? 1.f : __expf(l2)) : 0.f;
    float sp[kO + 1];
    sp[kO] = e1 + e2;
    #pragma unroll
    for (int o = 0; o < kO; ++o) sp[o] = e1 * P1[o] + e2 * P2[o];
    #pragma unroll
    for (int v = 0; v <= kO; ++v) {
      sp[v] = dpp_xor1_add(sp[v]);
      sp[v] = dpp_xor2_add(sp[v]);
    }
    if ((t & 3) == 0) {
      float* row = &red[(t >> 2) * RST];
      #pragma unroll
      for (int q = 0; q < 4; ++q)
        *reinterpret_cast<float4*>(row + 4 * q) =
            make_float4(sp[4*q], sp[4*q+1], sp[4*q+2], sp[4*q+3]);
      row[16] = sp[16];
    }
    __syncthreads();
    if (t < 136) {
      const int q = t / 17, col = t - q * 17;
      float a = 0.f;
      #pragma unroll
      for (int rr = 0; rr < 16; ++rr) a += red[(rr * 8 + q) * RST + col];
      red2[q * RST + col] = a;
    }
    __syncthreads();
    if (t < 17) {
      float a = 0.f;
      #pragma unroll
      for (int q = 0; q < 8; ++q) a += red2[q * RST + t];
      shs[t] = a;
    }
    __syncthreads();
    const float Zi = 1.f / shs[kO];
    float ss = 0.f;
    #pragma unroll
    for (int o = 0; o < kO; ++o) ss += shs[o] * shs[o];
    const float sn = ss * Zi * Zi;
    const float g  = Zi * sqrtf(sn) / (1.f + sn);
    if (it < NITER - 1) {
      float d1 = 0.f, d2 = 0.f;
      #pragma unroll
      for (int o = 0; o < kO; ++o) { d1 += P1[o] * shs[o]; d2 += P2[o] * shs[o]; }
      l1 += d1 * g;
      if (has2) l2 += d2 * g;
    } else {
      if (t < kO) out[(size_t)b * kO * kNC + t * kNC + c] = shs[t] * g;
    }
  }
}

}  // namespace

extern "C" void kernel_launch(void* const* d_in, const int* in_sizes, int n_in,
                              void* d_out, int out_size, void* d_ws, size_t ws_size,
                              hipStream_t stream) {
  const float* x = (const float*)d_in[0];   // [64, 8, 800] fp32
  const float* W = (const float*)d_in[1];   // [128, 800, 8, 16] fp32
  float* out = (float*)d_out;               // [64, 16, 128] fp32
  (void)in_sizes; (void)n_in; (void)out_size;

  if (ws_size >= WS_NEEDED) {
    unsigned short* Wb = (unsigned short*)d_ws;
    conv_w<<<dim3(kNC * 25), dim3(CT), 0, stream>>>(W, Wb);
    caps_route<<<dim3(kNC * kB), dim3(MT), 0, stream>>>(x, Wb, out);
  } else {
    caps_route_f32<<<dim3(kNC * kB), dim3(MT), 0, stream>>>(x, W, out);
  }
}